// Round 6
// baseline (1978.883 us; speedup 1.0000x reference)
//
#include <hip/hip_runtime.h>
#include <hip/hip_bf16.h>

// GroupGMM: B=8192, I=512, G=32, C=16, D=32; out = concat(pi[16], mu[512], softplus(sig)[512])
#define BATCH 8192
#define IDIM  512
#define GDIM  32
#define NOUT  1040
#define NPAD  1152     // 9 * 128 n-tiles
#define KW    16384    // G*I
#define BM    128
#define BN    128
#define IHALF 256      // I-half resident in LDS per outer pass
#define MBLKS 64       // BATCH/BM
#define NCOLS 9        // NPAD/BN

typedef short bf16x8 __attribute__((ext_vector_type(8)));   // 8 bf16 (4 VGPRs)
typedef float floatx4 __attribute__((ext_vector_type(4)));  // MFMA acc

__device__ inline unsigned pk2(float a, float b) {
    union { __hip_bfloat162 h2; unsigned u; } cv;
    cv.h2 = __float22bfloat162_rn(float2{a, b});
    return cv.u;
}

// ---- cvt fp32 -> bf16, 8 elems/thread (xb and gb) ---------------------------------
__global__ void cvt_bf16(const float* __restrict__ s, unsigned short* __restrict__ d) {
    int t = blockIdx.x * 256 + threadIdx.x;
    const float4* sp = (const float4*)s + (size_t)t * 2;
    float4 a = sp[0], b = sp[1];
    uint4 p;
    p.x = pk2(a.x, a.y); p.y = pk2(a.z, a.w);
    p.z = pk2(b.x, b.y); p.w = pk2(b.z, b.w);
    *(uint4*)(d + (size_t)t * 8) = p;
}

// ---- prep: Wt[n][16384] bf16 (weights only; zero-padded rows n>=1040) -------------
__global__ void prep_wt(const float* __restrict__ Wmu, const float* __restrict__ Wsig,
                        const float* __restrict__ Wpi, unsigned short* __restrict__ Wt) {
    int n = blockIdx.y * 256 + threadIdx.x;
    if (n >= NPAD) return;
    int k0 = blockIdx.x * 8;
    float v[8];
#pragma unroll
    for (int j = 0; j < 8; ++j) {
        int k = k0 + j, gg = k >> 9, i = k & 511;
        float val = 0.0f;
        if (n < 16)         val = Wpi [(gg * 512 + i) * 16  + n];
        else if (n < 528)   val = Wmu [(gg * 512 + i) * 512 + (n - 16)];
        else if (n < NOUT)  val = Wsig[(gg * 512 + i) * 512 + (n - 528)];
        v[j] = val;
    }
    uint4 p;
    p.x = pk2(v[0], v[1]); p.y = pk2(v[2], v[3]);
    p.z = pk2(v[4], v[5]); p.w = pk2(v[6], v[7]);
    *(uint4*)&Wt[(size_t)n * KW + k0] = p;
}

// ---- prep: Wb[n][32] bf16 = concatenated biases, n-major --------------------------
__global__ void prep_wb(const float* __restrict__ bmu, const float* __restrict__ bsig,
                        const float* __restrict__ bpi, unsigned short* __restrict__ Wb) {
    int n = blockIdx.y * 256 + threadIdx.x;
    if (n >= NPAD) return;
    int k0 = blockIdx.x * 8;
    float v[8];
#pragma unroll
    for (int j = 0; j < 8; ++j) {
        int gg = k0 + j;
        float val = 0.0f;
        if (n < 16)         val = bpi [gg * 16  + n];
        else if (n < 528)   val = bmu [gg * 512 + (n - 16)];
        else if (n < NOUT)  val = bsig[gg * 512 + (n - 528)];
        v[j] = val;
    }
    uint4 p;
    p.x = pk2(v[0], v[1]); p.y = pk2(v[2], v[3]);
    p.z = pk2(v[4], v[5]); p.w = pk2(v[6], v[7]);
    *(uint4*)&Wb[(size_t)n * GDIM + k0] = p;
}

// ---- GEMM: BM=128, A(I-half) LDS-resident, B streamed to VGPRs, XCD-pinned cols ---
// out[m,n] = sum_gg g[m,gg]*(xb[m,:] @ Wt_gg[:,n]) + gb[m,:] @ Wb[:,n]^T
__global__ __launch_bounds__(256, 2) void gemm_gmm(
        const unsigned short* __restrict__ xb, const unsigned short* __restrict__ gb,
        const float* __restrict__ g, const unsigned short* __restrict__ Wt,
        const unsigned short* __restrict__ Wb, float* __restrict__ out) {
    __shared__ unsigned short lA[BM * IHALF];      // 64 KB, XOR-swizzled 16B granules
    __shared__ unsigned short gscb[GDIM * BM];     // 8 KB bf16: [gg][row] scales

    const int t = threadIdx.x, lane = t & 63, w = t >> 6;
    const int wm = (w & 1) * 64, wn = (w >> 1) * 64;   // 4 waves: 2x2 of 64m x 64n
    const int q = lane >> 4, l15 = lane & 15;

    // XCD-locality remap: assume xcd = bx & 7 (round-robin). Each XCD gets 72
    // consecutive work items of the column-major (col, mblk) sequence -> its L2
    // holds ~1 n-column (2.1 MB Wt half-rows live per kb pass).
    const int bx = blockIdx.x;                 // 0..575
    const int seq = (bx & 7) * 72 + (bx >> 3); // 0..575
    const int col = seq >> 6, mblk = seq & 63;
    const int m0 = mblk * BM, n0 = col * BN;

    // ---- scales -> LDS as bf16, [gg][row] --------------------------------------
#pragma unroll
    for (int j = 0; j < 16; ++j) {
        int idx = t * 16 + j;                  // idx = gg*128 + row
        int gg = idx >> 7, row = idx & 127;
        __hip_bfloat16 h = __float2bfloat16(g[(size_t)(m0 + row) * GDIM + gg]);
        gscb[idx] = *(unsigned short*)&h;
    }

    // ---- B row byte-offsets (16B-contiguous k-runs of n-major Wt) ---------------
    size_t rowOff[4];
#pragma unroll
    for (int tn = 0; tn < 4; ++tn)
        rowOff[tn] = (size_t)(n0 + wn + tn * 16 + l15) * KW + q * 8;

    uint4 breg[2][2][4];                       // [slot][ks][tn] : depth-2 rotation
    floatx4 acc[4][4] = {};
    floatx4 P[4][4] = {};
    const int swA = l15 & 7;

    for (int kb = 0; kb < 2; ++kb) {
        // ---- stage A I-half into LDS (2 barriers; none inside the chunk loop) ---
        __syncthreads();                       // lA reads from previous kb complete
        {
            const int r = t >> 1;
            const unsigned short* src = xb + (size_t)(m0 + r) * IDIM + kb * IHALF;
#pragma unroll
            for (int j = 0; j < 16; ++j) {
                int gi = (t & 1) * 16 + j;     // granule 0..31
                uint4 v = *(const uint4*)(src + gi * 8);
                *(uint4*)&lA[(r * 32 + (gi ^ (r & 7))) * 8] = v;
            }
        }
        __syncthreads();

        // chunk c (0..127): group gg = c>>2, k = gg*512 + kb*256 + (c&3)*64
        auto loadB = [&](int c, int slot) {
            const size_t k = (size_t)((c >> 2) * 512 + kb * 256 + (c & 3) * 64);
#pragma unroll
            for (int ks = 0; ks < 2; ++ks)
#pragma unroll
                for (int tn = 0; tn < 4; ++tn)
                    breg[slot][ks][tn] = *(const uint4*)(Wt + rowOff[tn] + k + ks * 32);
        };
        loadB(0, 0); loadB(1, 1);

        for (int c = 0; c < 128; ++c) {
            const int slot = c & 1, ac = (c & 3) * 8;
#pragma unroll
            for (int ks = 0; ks < 2; ++ks) {
                bf16x8 af[4];
#pragma unroll
                for (int tm = 0; tm < 4; ++tm) {
                    int gi = ac + ks * 4 + q;
                    af[tm] = *(const bf16x8*)&lA[((wm + tm * 16 + l15) * 32 + (gi ^ swA)) * 8];
                }
#pragma unroll
                for (int tm = 0; tm < 4; ++tm)
#pragma unroll
                    for (int tn = 0; tn < 4; ++tn)
                        P[tm][tn] = __builtin_amdgcn_mfma_f32_16x16x32_bf16(
                            af[tm], *(const bf16x8*)&breg[slot][ks][tn], P[tm][tn], 0, 0, 0);
            }
            if (c + 2 < 128) loadB(c + 2, slot);   // flight >= 1 full chunk, no vmcnt(0)
            if ((c & 3) == 3) {                    // group-half boundary: merge
                const int gg = c >> 2;
#pragma unroll
                for (int tm = 0; tm < 4; ++tm) {
                    float s[4];
#pragma unroll
                    for (int r = 0; r < 4; ++r) {  // scalar u16 broadcast reads: free
                        unsigned short u = gscb[gg * 128 + wm + tm * 16 + q * 4 + r];
                        s[r] = __bfloat162float(*(__hip_bfloat16*)&u);
                    }
#pragma unroll
                    for (int tn = 0; tn < 4; ++tn) {
#pragma unroll
                        for (int r = 0; r < 4; ++r)
                            acc[tm][tn][r] += s[r] * P[tm][tn][r];
                        P[tm][tn] = (floatx4){0.f, 0.f, 0.f, 0.f};
                    }
                }
            }
        }
    }

    // ---- bias: stage gb tile into lA (stride 40), one K=32 MFMA per frag ---------
    __syncthreads();
    {
        const int r = t >> 1;
        const unsigned short* src = gb + (size_t)(m0 + r) * GDIM + (t & 1) * 16;
        *(uint4*)&lA[r * 40 + (t & 1) * 16]     = *(const uint4*)(src);
        *(uint4*)&lA[r * 40 + (t & 1) * 16 + 8] = *(const uint4*)(src + 8);
    }
    __syncthreads();
    {
        bf16x8 afb[4], bb[4];
#pragma unroll
        for (int tm = 0; tm < 4; ++tm)
            afb[tm] = *(const bf16x8*)&lA[(wm + tm * 16 + l15) * 40 + q * 8];
#pragma unroll
        for (int tn = 0; tn < 4; ++tn)
            bb[tn] = *(const bf16x8*)(Wb + (size_t)(n0 + wn + tn * 16 + l15) * GDIM + q * 8);
#pragma unroll
        for (int tm = 0; tm < 4; ++tm)
#pragma unroll
            for (int tn = 0; tn < 4; ++tn)
                acc[tm][tn] = __builtin_amdgcn_mfma_f32_16x16x32_bf16(
                    afb[tm], bb[tn], acc[tm][tn], 0, 0, 0);
    }

    // ---- epilogue: fused softplus on sigma region, direct store ------------------
#pragma unroll
    for (int tn = 0; tn < 4; ++tn) {
        int n = n0 + wn + tn * 16 + l15;
        if (n >= NOUT) continue;
        bool is_scale = (n >= 528);
#pragma unroll
        for (int tm = 0; tm < 4; ++tm) {
            int mbase = m0 + wm + tm * 16 + q * 4;
#pragma unroll
            for (int r = 0; r < 4; ++r) {
                float vv = acc[tm][tn][r];
                if (is_scale) {
                    float sp = (vv > 15.0f) ? vv : log1pf(expf(vv));
                    vv = sp + 1e-7f;
                }
                out[(size_t)(mbase + r) * NOUT + n] = vv;
            }
        }
    }
}

extern "C" void kernel_launch(void* const* d_in, const int* in_sizes, int n_in,
                              void* d_out, int out_size, void* d_ws, size_t ws_size,
                              hipStream_t stream) {
    const float* x    = (const float*)d_in[0];
    const float* g    = (const float*)d_in[1];
    const float* Wmu  = (const float*)d_in[2];
    const float* bmu  = (const float*)d_in[3];
    const float* Wsig = (const float*)d_in[4];
    const float* bsig = (const float*)d_in[5];
    const float* Wpi  = (const float*)d_in[6];
    const float* bpi  = (const float*)d_in[7];
    float* out = (float*)d_out;

    // workspace (~46.3 MB)
    char* ws = (char*)d_ws;
    unsigned short* Wt = (unsigned short*)ws;  ws += (size_t)NPAD * KW * 2;     // 37.75 MB
    unsigned short* xb = (unsigned short*)ws;  ws += (size_t)BATCH * IDIM * 2;  //  8.0 MB
    unsigned short* gb = (unsigned short*)ws;  ws += (size_t)BATCH * GDIM * 2;  //  0.5 MB
    unsigned short* Wb = (unsigned short*)ws;                                   //  0.07 MB

    cvt_bf16<<<BATCH * IDIM / 2048, 256, 0, stream>>>(x, xb);
    cvt_bf16<<<BATCH * GDIM / 2048, 256, 0, stream>>>(g, gb);
    prep_wt<<<dim3(KW / 8, 5), 256, 0, stream>>>(Wmu, Wsig, Wpi, Wt);
    prep_wb<<<dim3(GDIM / 8, 5), 256, 0, stream>>>(bmu, bsig, bpi, Wb);
    gemm_gmm<<<MBLKS * NCOLS, 256, 0, stream>>>(xb, gb, g, Wt, Wb, out);
}

// Round 7
// 1341.301 us; speedup vs baseline: 1.4753x; 1.4753x over previous
//
#include <hip/hip_runtime.h>
#include <hip/hip_bf16.h>

// GroupGMM: B=8192, I=512, G=32, C=16, D=32; out = concat(pi[16], mu[512], softplus(sig)[512])
#define BATCH 8192
#define IDIM  512
#define GDIM  32
#define NOUT  1040
#define NPAD  1152     // 9 * 128 n-tiles
#define KW    16384    // G*I
#define BM    128
#define BN    128
#define KQ    128      // I-quarter resident in LDS per outer pass

typedef short bf16x8 __attribute__((ext_vector_type(8)));   // 8 bf16 (4 VGPRs)
typedef float floatx4 __attribute__((ext_vector_type(4)));  // MFMA acc

__device__ inline unsigned pk2(float a, float b) {
    union { __hip_bfloat162 h2; unsigned u; } cv;
    cv.h2 = __float22bfloat162_rn(float2{a, b});
    return cv.u;
}

// ---- cvt fp32 -> bf16, 8 elems/thread (xb and gb) ---------------------------------
__global__ void cvt_bf16(const float* __restrict__ s, unsigned short* __restrict__ d) {
    int t = blockIdx.x * 256 + threadIdx.x;
    const float4* sp = (const float4*)s + (size_t)t * 2;
    float4 a = sp[0], b = sp[1];
    uint4 p;
    p.x = pk2(a.x, a.y); p.y = pk2(a.z, a.w);
    p.z = pk2(b.x, b.y); p.w = pk2(b.z, b.w);
    *(uint4*)(d + (size_t)t * 8) = p;
}

// ---- prep: Wt[n][16384] bf16 (weights only; zero-padded rows n>=1040) -------------
__global__ void prep_wt(const float* __restrict__ Wmu, const float* __restrict__ Wsig,
                        const float* __restrict__ Wpi, unsigned short* __restrict__ Wt) {
    int n = blockIdx.y * 256 + threadIdx.x;
    if (n >= NPAD) return;
    int k0 = blockIdx.x * 8;
    float v[8];
#pragma unroll
    for (int j = 0; j < 8; ++j) {
        int k = k0 + j, gg = k >> 9, i = k & 511;
        float val = 0.0f;
        if (n < 16)         val = Wpi [(gg * 512 + i) * 16  + n];
        else if (n < 528)   val = Wmu [(gg * 512 + i) * 512 + (n - 16)];
        else if (n < NOUT)  val = Wsig[(gg * 512 + i) * 512 + (n - 528)];
        v[j] = val;
    }
    uint4 p;
    p.x = pk2(v[0], v[1]); p.y = pk2(v[2], v[3]);
    p.z = pk2(v[4], v[5]); p.w = pk2(v[6], v[7]);
    *(uint4*)&Wt[(size_t)n * KW + k0] = p;
}

// ---- prep: Wb[n][32] bf16 = concatenated biases, n-major --------------------------
__global__ void prep_wb(const float* __restrict__ bmu, const float* __restrict__ bsig,
                        const float* __restrict__ bpi, unsigned short* __restrict__ Wb) {
    int n = blockIdx.y * 256 + threadIdx.x;
    if (n >= NPAD) return;
    int k0 = blockIdx.x * 8;
    float v[8];
#pragma unroll
    for (int j = 0; j < 8; ++j) {
        int gg = k0 + j;
        float val = 0.0f;
        if (n < 16)         val = bpi [gg * 16  + n];
        else if (n < 528)   val = bmu [gg * 512 + (n - 16)];
        else if (n < NOUT)  val = bsig[gg * 512 + (n - 528)];
        v[j] = val;
    }
    uint4 p;
    p.x = pk2(v[0], v[1]); p.y = pk2(v[2], v[3]);
    p.z = pk2(v[4], v[5]); p.w = pk2(v[6], v[7]);
    *(uint4*)&Wb[(size_t)n * GDIM + k0] = p;
}

// ---- GEMM: A I-quarter LDS-resident, B double-buffered in VGPRs, XCD-pinned -------
// out[m,n] = sum_gg g[m,gg]*(xb[m,:] @ Wt_gg[:,n]) + gb[m,:] @ Wb[:,n]^T
__global__ __launch_bounds__(256, 2) void gemm_gmm(
        const unsigned short* __restrict__ xb, const unsigned short* __restrict__ gb,
        const float* __restrict__ g, const unsigned short* __restrict__ Wt,
        const unsigned short* __restrict__ Wb, float* __restrict__ out) {
    __shared__ unsigned short lA[BM * KQ];     // 32 KB, XOR-swizzled 16B granules
    __shared__ float gsc[GDIM * BM];           // 16 KB f32: [gg][row]

    const int t = threadIdx.x, lane = t & 63, w = t >> 6;
    const int wm = (w & 1) * 64, wn = (w >> 1) * 64;   // 2x2 waves of 64m x 64n
    const int q = lane >> 4, l15 = lane & 15;

    // XCD pinning (xcd = bx & 7 round-robin): each XCD walks mblk-major within
    // ~1.125 n-columns -> active 1 MB Wt column-quarter stays in its 4 MB L2.
    const int bx = blockIdx.x;                  // 0..575
    const int seq = (bx & 7) * 72 + (bx >> 3);  // bijection 0..575
    const int col = seq >> 6, mblk = seq & 63;
    const int m0 = mblk * BM, n0 = col * BN;

    // ---- scales -> LDS f32, [gg][row]: merge reads are contiguous float4 ---------
#pragma unroll
    for (int j = 0; j < 16; ++j) {
        int idx = t + 256 * j;                  // idx = gg*128 + row
        int gg = idx >> 7, row = idx & 127;
        gsc[idx] = g[(size_t)(m0 + row) * GDIM + gg];
    }

    // ---- B row offsets (shorts): 16B-contiguous k-runs of n-major Wt -------------
    unsigned rowOff[4];
#pragma unroll
    for (int tn = 0; tn < 4; ++tn)
        rowOff[tn] = (unsigned)(n0 + wn + tn * 16 + l15) * KW + q * 8;

    floatx4 acc[4][4] = {};
    floatx4 P[4][4] = {};
    uint4 breg[2][4];                           // double-buffered B step (32 VGPRs)
    const int swA = l15 & 7;

    // flattened k-step index kk = ((kb*32+gg)*4+ks), kk in [0,512)
    auto koff = [](int kk) -> unsigned {
        return (unsigned)((((kk >> 2) & 31) * 512) + ((kk >> 7) * KQ) + ((kk & 3) * 32));
    };
    auto loadB = [&](int kk, int slot) {
        const unsigned k = koff(kk);
#pragma unroll
        for (int tn = 0; tn < 4; ++tn)
            breg[slot][tn] = *(const uint4*)(Wt + rowOff[tn] + k);
    };

    loadB(0, 0);
    for (int kb = 0; kb < 4; ++kb) {
        __syncthreads();                        // prior kb's lA reads complete
        {   // stage A quarter: row = t>>1, granules gi = (t&1)*8 + j
            const int r = t >> 1;
            const unsigned short* src = xb + (size_t)(m0 + r) * IDIM + kb * KQ + (t & 1) * 64;
#pragma unroll
            for (int j = 0; j < 8; ++j) {
                int gi = (t & 1) * 8 + j;
                uint4 v = *(const uint4*)(src + j * 8);
                *(uint4*)&lA[(r * 16 + (gi ^ (r & 7))) * 8] = v;
            }
        }
        __syncthreads();

        for (int gg = 0; gg < GDIM; ++gg) {
#pragma unroll
            for (int ks = 0; ks < 4; ++ks) {
                const int kk = ((kb * GDIM + gg) << 2) + ks;
                if (kk + 1 < 512) loadB(kk + 1, (kk + 1) & 1);  // prefetch next step
                bf16x8 af[4];
#pragma unroll
                for (int tm = 0; tm < 4; ++tm)
                    af[tm] = *(const bf16x8*)
                        &lA[((wm + tm * 16 + l15) * 16 + ((ks * 4 + q) ^ swA)) * 8];
                const int slot = kk & 1;
#pragma unroll
                for (int tm = 0; tm < 4; ++tm)
#pragma unroll
                    for (int tn = 0; tn < 4; ++tn)
                        P[tm][tn] = __builtin_amdgcn_mfma_f32_16x16x32_bf16(
                            af[tm], *(const bf16x8*)&breg[slot][tn], P[tm][tn], 0, 0, 0);
            }
            // group-quarter boundary: acc += g[m,gg] * P (f32), rezero P
#pragma unroll
            for (int tm = 0; tm < 4; ++tm) {
                floatx4 s4 = *(const floatx4*)&gsc[gg * BM + wm + tm * 16 + q * 4];
#pragma unroll
                for (int tn = 0; tn < 4; ++tn) {
#pragma unroll
                    for (int r = 0; r < 4; ++r)
                        acc[tm][tn][r] += s4[r] * P[tm][tn][r];
                    P[tm][tn] = (floatx4){0.f, 0.f, 0.f, 0.f};
                }
            }
        }
    }

    // ---- bias: stage gb tile into lA (stride 40), one K=32 MFMA per frag ---------
    __syncthreads();
    {
        const int r = t >> 1;
        const unsigned short* src = gb + (size_t)(m0 + r) * GDIM + (t & 1) * 16;
        *(uint4*)&lA[r * 40 + (t & 1) * 16]     = *(const uint4*)(src);
        *(uint4*)&lA[r * 40 + (t & 1) * 16 + 8] = *(const uint4*)(src + 8);
    }
    __syncthreads();
    {
        bf16x8 afb[4], bb[4];
#pragma unroll
        for (int tm = 0; tm < 4; ++tm)
            afb[tm] = *(const bf16x8*)&lA[(wm + tm * 16 + l15) * 40 + q * 8];
#pragma unroll
        for (int tn = 0; tn < 4; ++tn)
            bb[tn] = *(const bf16x8*)(Wb + (size_t)(n0 + wn + tn * 16 + l15) * GDIM + q * 8);
#pragma unroll
        for (int tm = 0; tm < 4; ++tm)
#pragma unroll
            for (int tn = 0; tn < 4; ++tn)
                acc[tm][tn] = __builtin_amdgcn_mfma_f32_16x16x32_bf16(
                    afb[tm], bb[tn], acc[tm][tn], 0, 0, 0);
    }

    // ---- epilogue: fused softplus on sigma region, direct store ------------------
#pragma unroll
    for (int tn = 0; tn < 4; ++tn) {
        int n = n0 + wn + tn * 16 + l15;
        if (n >= NOUT) continue;
        bool is_scale = (n >= 528);
#pragma unroll
        for (int tm = 0; tm < 4; ++tm) {
            int mbase = m0 + wm + tm * 16 + q * 4;
#pragma unroll
            for (int r = 0; r < 4; ++r) {
                float vv = acc[tm][tn][r];
                if (is_scale) {
                    float sp = (vv > 15.0f) ? vv : log1pf(expf(vv));
                    vv = sp + 1e-7f;
                }
                out[(size_t)(mbase + r) * NOUT + n] = vv;
            }
        }
    }
}

extern "C" void kernel_launch(void* const* d_in, const int* in_sizes, int n_in,
                              void* d_out, int out_size, void* d_ws, size_t ws_size,
                              hipStream_t stream) {
    const float* x    = (const float*)d_in[0];
    const float* g    = (const float*)d_in[1];
    const float* Wmu  = (const float*)d_in[2];
    const float* bmu  = (const float*)d_in[3];
    const float* Wsig = (const float*)d_in[4];
    const float* bsig = (const float*)d_in[5];
    const float* Wpi  = (const float*)d_in[6];
    const float* bpi  = (const float*)d_in[7];
    float* out = (float*)d_out;

    // workspace (~46.3 MB)
    char* ws = (char*)d_ws;
    unsigned short* Wt = (unsigned short*)ws;  ws += (size_t)NPAD * KW * 2;     // 37.75 MB
    unsigned short* xb = (unsigned short*)ws;  ws += (size_t)BATCH * IDIM * 2;  //  8.0 MB
    unsigned short* gb = (unsigned short*)ws;  ws += (size_t)BATCH * GDIM * 2;  //  0.5 MB
    unsigned short* Wb = (unsigned short*)ws;                                   //  0.07 MB

    cvt_bf16<<<BATCH * IDIM / 2048, 256, 0, stream>>>(x, xb);
    cvt_bf16<<<BATCH * GDIM / 2048, 256, 0, stream>>>(g, gb);
    prep_wt<<<dim3(KW / 8, 5), 256, 0, stream>>>(Wmu, Wsig, Wpi, Wt);
    prep_wb<<<dim3(GDIM / 8, 5), 256, 0, stream>>>(bmu, bsig, bpi, Wb);
    gemm_gmm<<<(BATCH / BM) * (NPAD / BN), 256, 0, stream>>>(xb, gb, g, Wt, Wb, out);
}

// Round 8
// 563.058 us; speedup vs baseline: 3.5145x; 2.3822x over previous
//
#include <hip/hip_runtime.h>
#include <hip/hip_bf16.h>

// GroupGMM: B=8192, I=512, G=32, C=16, D=32; out = concat(pi[16], mu[512], softplus(sig)[512])
#define BATCH 8192
#define IDIM  512
#define GDIM  32
#define NOUT  1040
#define NPAD  1152     // 9 * 128 n-tiles
#define KW    16384    // G*I
#define BM    128
#define BN    128
#define KQ    128      // I-quarter resident in LDS per outer pass

typedef short bf16x8 __attribute__((ext_vector_type(8)));   // 8 bf16 (4 VGPRs)
typedef float floatx4 __attribute__((ext_vector_type(4)));  // MFMA acc

__device__ inline unsigned pk2(float a, float b) {
    union { __hip_bfloat162 h2; unsigned u; } cv;
    cv.h2 = __float22bfloat162_rn(float2{a, b});
    return cv.u;
}

// ---- cvt fp32 -> bf16, 8 elems/thread (xb and gb) ---------------------------------
__global__ void cvt_bf16(const float* __restrict__ s, unsigned short* __restrict__ d) {
    int t = blockIdx.x * 256 + threadIdx.x;
    const float4* sp = (const float4*)s + (size_t)t * 2;
    float4 a = sp[0], b = sp[1];
    uint4 p;
    p.x = pk2(a.x, a.y); p.y = pk2(a.z, a.w);
    p.z = pk2(b.x, b.y); p.w = pk2(b.z, b.w);
    *(uint4*)(d + (size_t)t * 8) = p;
}

// ---- prep: Bpack — per K=32-step 8 KB lane-ordered slabs --------------------------
// idx(n,k): col=n>>7, r=n&127 -> h=r>>6, tn=(r>>4)&3, l15=r&15; kk=k>>5, q=(k>>3)&3,
//           j=k&7 ->  (col*512+kk)*4096 + (((h*4+tn)*4+q)*16 + l15)*8 + j
__global__ void prep_wt(const float* __restrict__ Wmu, const float* __restrict__ Wsig,
                        const float* __restrict__ Wpi, unsigned short* __restrict__ Wt) {
    int n = blockIdx.y * 256 + threadIdx.x;
    if (n >= NPAD) return;
    int k0 = blockIdx.x * 8;
    float v[8];
#pragma unroll
    for (int j = 0; j < 8; ++j) {
        int k = k0 + j, gg = k >> 9, i = k & 511;
        float val = 0.0f;
        if (n < 16)         val = Wpi [(gg * 512 + i) * 16  + n];
        else if (n < 528)   val = Wmu [(gg * 512 + i) * 512 + (n - 16)];
        else if (n < NOUT)  val = Wsig[(gg * 512 + i) * 512 + (n - 528)];
        v[j] = val;
    }
    uint4 p;
    p.x = pk2(v[0], v[1]); p.y = pk2(v[2], v[3]);
    p.z = pk2(v[4], v[5]); p.w = pk2(v[6], v[7]);
    const int col = n >> 7, r = n & 127;
    const int h = r >> 6, tn = (r >> 4) & 3, l15 = r & 15;
    const int kk = k0 >> 5, q = (k0 >> 3) & 3;
    size_t idx = ((size_t)(col * 512 + kk) << 12) + ((((h * 4 + tn) * 4 + q) * 16 + l15) * 8);
    *(uint4*)&Wt[idx] = p;
}

// ---- prep: Wb[n][32] bf16 = concatenated biases, n-major --------------------------
__global__ void prep_wb(const float* __restrict__ bmu, const float* __restrict__ bsig,
                        const float* __restrict__ bpi, unsigned short* __restrict__ Wb) {
    int n = blockIdx.y * 256 + threadIdx.x;
    if (n >= NPAD) return;
    int k0 = blockIdx.x * 8;
    float v[8];
#pragma unroll
    for (int j = 0; j < 8; ++j) {
        int gg = k0 + j;
        float val = 0.0f;
        if (n < 16)         val = bpi [gg * 16  + n];
        else if (n < 528)   val = bmu [gg * 512 + (n - 16)];
        else if (n < NOUT)  val = bsig[gg * 512 + (n - 528)];
        v[j] = val;
    }
    uint4 p;
    p.x = pk2(v[0], v[1]); p.y = pk2(v[2], v[3]);
    p.z = pk2(v[4], v[5]); p.w = pk2(v[6], v[7]);
    *(uint4*)&Wb[(size_t)n * GDIM + k0] = p;
}

// ---- GEMM: A I-quarter LDS-resident, B streamed (packed, coalesced), XCD-pinned ---
// out[m,n] = sum_gg g[m,gg]*(xb[m,:] @ W_gg[:,n]) + gb[m,:] @ Wb[:,n]^T
__global__ __launch_bounds__(256, 2) void gemm_gmm(
        const unsigned short* __restrict__ xb, const unsigned short* __restrict__ gb,
        const float* __restrict__ g, const unsigned short* __restrict__ Wt,
        const unsigned short* __restrict__ Wb, float* __restrict__ out) {
    __shared__ unsigned short lA[BM * KQ];     // 32 KB, XOR-swizzled 16B granules
    __shared__ float gsc[GDIM * BM];           // 16 KB f32: [gg][row]

    const int t = threadIdx.x, lane = t & 63, w = t >> 6;
    const int wm = (w & 1) * 64, wn = (w >> 1) * 64;   // 2x2 waves of 64m x 64n
    const int q = lane >> 4, l15 = lane & 15;

    // XCD pinning (xcd = bx & 7 round-robin): each XCD walks mblk-major within
    // ~1.125 n-columns -> active Wt slabs stay in its 4 MB L2.
    const int bx = blockIdx.x;                  // 0..575
    const int seq = (bx & 7) * 72 + (bx >> 3);  // bijection 0..575
    const int col = seq >> 6, mblk = seq & 63;
    const int m0 = mblk * BM, n0 = col * BN;

    // ---- scales -> LDS f32, [gg][row] -------------------------------------------
#pragma unroll
    for (int j = 0; j < 16; ++j) {
        int idx = t + 256 * j;                  // idx = gg*128 + row
        int gg = idx >> 7, row = idx & 127;
        gsc[idx] = g[(size_t)(m0 + row) * GDIM + gg];
    }

    // ---- B base: per-step 8 KB slab; this wave's lane offset ----------------------
    const unsigned short* Bbase = Wt + ((size_t)col * 512 << 12)
                                + (((wn >> 6) * 256 + lane) * 8);

    floatx4 acc[4][4] = {};
    floatx4 P[4][4] = {};
    uint4 breg[2][4];                           // double-buffered B step (32 VGPRs)
    const int swA = l15 & 7;

    // flat kk = ((kb*32+gg)<<2)+ks  ->  global step kg = gg*16 + kb*4 + ks
    auto loadB = [&](int kk, int slot) {
        const unsigned kg = (((kk >> 2) & 31) * 16) + ((kk >> 7) * 4) + (kk & 3);
        const unsigned short* p = Bbase + ((size_t)kg << 12);
#pragma unroll
        for (int tn = 0; tn < 4; ++tn)
            breg[slot][tn] = *(const uint4*)(p + tn * 512);  // imm offsets 0/1/2/3 KB
    };

    loadB(0, 0);
    for (int kb = 0; kb < 4; ++kb) {
        __syncthreads();                        // prior kb's lA reads complete
        {   // stage A quarter: row = t>>1, granules gi = (t&1)*8 + j
            const int r = t >> 1;
            const unsigned short* src = xb + (size_t)(m0 + r) * IDIM + kb * KQ + (t & 1) * 64;
#pragma unroll
            for (int j = 0; j < 8; ++j) {
                int gi = (t & 1) * 8 + j;
                uint4 v = *(const uint4*)(src + j * 8);
                *(uint4*)&lA[(r * 16 + (gi ^ (r & 7))) * 8] = v;
            }
        }
        __syncthreads();

        for (int gg = 0; gg < GDIM; ++gg) {
#pragma unroll
            for (int ks = 0; ks < 4; ++ks) {
                const int kk = ((kb * GDIM + gg) << 2) + ks;
                if (kk + 1 < 512) loadB(kk + 1, (kk + 1) & 1);  // prefetch next step
                bf16x8 af[4];
#pragma unroll
                for (int tm = 0; tm < 4; ++tm)
                    af[tm] = *(const bf16x8*)
                        &lA[((wm + tm * 16 + l15) * 16 + ((ks * 4 + q) ^ swA)) * 8];
                const int slot = kk & 1;
#pragma unroll
                for (int tm = 0; tm < 4; ++tm)
#pragma unroll
                    for (int tn = 0; tn < 4; ++tn)
                        P[tm][tn] = __builtin_amdgcn_mfma_f32_16x16x32_bf16(
                            af[tm], *(const bf16x8*)&breg[slot][tn], P[tm][tn], 0, 0, 0);
            }
            // group-quarter boundary: acc += g[m,gg] * P (f32), rezero P
#pragma unroll
            for (int tm = 0; tm < 4; ++tm) {
                floatx4 s4 = *(const floatx4*)&gsc[gg * BM + wm + tm * 16 + q * 4];
#pragma unroll
                for (int tn = 0; tn < 4; ++tn) {
#pragma unroll
                    for (int r = 0; r < 4; ++r)
                        acc[tm][tn][r] += s4[r] * P[tm][tn][r];
                    P[tm][tn] = (floatx4){0.f, 0.f, 0.f, 0.f};
                }
            }
        }
    }

    // ---- bias: stage gb tile into lA (stride 40), one K=32 MFMA per frag ---------
    __syncthreads();
    {
        const int r = t >> 1;
        const unsigned short* src = gb + (size_t)(m0 + r) * GDIM + (t & 1) * 16;
        *(uint4*)&lA[r * 40 + (t & 1) * 16]     = *(const uint4*)(src);
        *(uint4*)&lA[r * 40 + (t & 1) * 16 + 8] = *(const uint4*)(src + 8);
    }
    __syncthreads();
    {
        bf16x8 afb[4], bb[4];
#pragma unroll
        for (int tm = 0; tm < 4; ++tm)
            afb[tm] = *(const bf16x8*)&lA[(wm + tm * 16 + l15) * 40 + q * 8];
#pragma unroll
        for (int tn = 0; tn < 4; ++tn)
            bb[tn] = *(const bf16x8*)(Wb + (size_t)(n0 + wn + tn * 16 + l15) * GDIM + q * 8);
#pragma unroll
        for (int tm = 0; tm < 4; ++tm)
#pragma unroll
            for (int tn = 0; tn < 4; ++tn)
                acc[tm][tn] = __builtin_amdgcn_mfma_f32_16x16x32_bf16(
                    afb[tm], bb[tn], acc[tm][tn], 0, 0, 0);
    }

    // ---- epilogue: fused softplus on sigma region, direct store ------------------
#pragma unroll
    for (int tn = 0; tn < 4; ++tn) {
        int n = n0 + wn + tn * 16 + l15;
        if (n >= NOUT) continue;
        bool is_scale = (n >= 528);
#pragma unroll
        for (int tm = 0; tm < 4; ++tm) {
            int mbase = m0 + wm + tm * 16 + q * 4;
#pragma unroll
            for (int r = 0; r < 4; ++r) {
                float vv = acc[tm][tn][r];
                if (is_scale) {
                    float sp = (vv > 15.0f) ? vv : log1pf(expf(vv));
                    vv = sp + 1e-7f;
                }
                out[(size_t)(mbase + r) * NOUT + n] = vv;
            }
        }
    }
}

extern "C" void kernel_launch(void* const* d_in, const int* in_sizes, int n_in,
                              void* d_out, int out_size, void* d_ws, size_t ws_size,
                              hipStream_t stream) {
    const float* x    = (const float*)d_in[0];
    const float* g    = (const float*)d_in[1];
    const float* Wmu  = (const float*)d_in[2];
    const float* bmu  = (const float*)d_in[3];
    const float* Wsig = (const float*)d_in[4];
    const float* bsig = (const float*)d_in[5];
    const float* Wpi  = (const float*)d_in[6];
    const float* bpi  = (const float*)d_in[7];
    float* out = (float*)d_out;

    // workspace (~46.3 MB)
    char* ws = (char*)d_ws;
    unsigned short* Wt = (unsigned short*)ws;  ws += (size_t)NPAD * KW * 2;     // 37.75 MB
    unsigned short* xb = (unsigned short*)ws;  ws += (size_t)BATCH * IDIM * 2;  //  8.0 MB
    unsigned short* gb = (unsigned short*)ws;  ws += (size_t)BATCH * GDIM * 2;  //  0.5 MB
    unsigned short* Wb = (unsigned short*)ws;                                   //  0.07 MB

    cvt_bf16<<<BATCH * IDIM / 2048, 256, 0, stream>>>(x, xb);
    cvt_bf16<<<BATCH * GDIM / 2048, 256, 0, stream>>>(g, gb);
    prep_wt<<<dim3(KW / 8, 5), 256, 0, stream>>>(Wmu, Wsig, Wpi, Wt);
    prep_wb<<<dim3(GDIM / 8, 5), 256, 0, stream>>>(bmu, bsig, bpi, Wb);
    gemm_gmm<<<(BATCH / BM) * (NPAD / BN), 256, 0, stream>>>(xb, gb, g, Wt, Wb, out);
}